// Round 6
// baseline (552.974 us; speedup 1.0000x reference)
//
#include <hip/hip_runtime.h>
#include <cstdint>

#define BB 64
#define SS 512
#define HH 512
#define EE 512
#define BSH (BB*SS*HH)

typedef _Float16 f16x8 __attribute__((ext_vector_type(8)));
typedef float    f32x4 __attribute__((ext_vector_type(4)));
typedef int      iv4   __attribute__((ext_vector_type(4)));
typedef unsigned long long u64;

__device__ __forceinline__ f16x8 pack8(float4 u, float4 v) {
    f16x8 h;
    h[0] = (_Float16)u.x; h[1] = (_Float16)u.y;
    h[2] = (_Float16)u.z; h[3] = (_Float16)u.w;
    h[4] = (_Float16)v.x; h[5] = (_Float16)v.y;
    h[6] = (_Float16)v.z; h[7] = (_Float16)v.w;
    return h;
}

// W scale: |W| <= 1/sqrt(512); map to [-127,127]
#define SW (127.0f * 22.627416997969522f)

__device__ __forceinline__ int quanw(float x) {
    return (int)rintf(fminf(fmaxf(x * SW, -127.0f), 127.0f));
}
__device__ __forceinline__ int packw4(float4 f) {
    int q0 = quanw(f.x), q1 = quanw(f.y), q2 = quanw(f.z), q3 = quanw(f.w);
    return (q0 & 255) | ((q1 & 255) << 8) | ((q2 & 255) << 16) | (q3 << 24);
}

// async global->LDS, 16B per lane (LDS dest = wave-uniform base + lane*16).
__device__ __forceinline__ void gload16(const void* g, void* l) {
    __builtin_amdgcn_global_load_lds(
        (const __attribute__((address_space(1))) void*)g,
        (__attribute__((address_space(3))) void*)l, 16, 0, 0);
}

// poll a monotone tile counter (relaxed), then one acquire fence.
// 4 polls per phase2 WG total -- NOT per-step (R4 lesson).
__device__ __forceinline__ void wait_tile(const unsigned int* c, unsigned int tgt) {
    while (__hip_atomic_load(c, __ATOMIC_RELAXED, __HIP_MEMORY_SCOPE_AGENT) < tgt) {
        __builtin_amdgcn_s_sleep(2);
    }
    __builtin_amdgcn_fence(__ATOMIC_ACQUIRE, "agent");
}

// ---------------- prep: f32->f16 pre-pass into workspace.
// a16[m][e] = (f16)emb[idx[m]][e]  (32768x512, 32 MB); b16 = (f16)Wih.
__global__ __launch_bounds__(256) void prep(
    const int* __restrict__ idx, const float* __restrict__ emb,
    const float* __restrict__ Wih, _Float16* __restrict__ a16,
    _Float16* __restrict__ b16) {
    const int bid = blockIdx.x, tid = threadIdx.x;
    if (bid < 8192) {
        int e = bid * 2048 + tid * 8;
        int m = e >> 9, c = e & 511;
        int gi = idx[m];
        const float* s = emb + (size_t)gi * EE + c;
        float4 u = *(const float4*)s, v = *(const float4*)(s + 4);
        *(f16x8*)(a16 + e) = pack8(u, v);
    } else {
        int e = (bid - 8192) * 2048 + tid * 8;
        float4 u = *(const float4*)(Wih + e), v = *(const float4*)(Wih + e + 4);
        *(f16x8*)(b16 + e) = pack8(u, v);
    }
}

// ---------------- FUSED kernel: bids 0..63 = phase2 role (1 batch each);
// bids 64..1087 = phase1 role (one 128x128 xp tile each, s-tile-major order).
// phase2 consumes xp tile st only after cnt[st]==256 (acquire); phase1 WGs
// signal with release fence + atomicAdd. One-way dependency -> deadlock-free
// (phase1 WGs wait on nothing; 192+ CUs available to them).
__global__ __launch_bounds__(512, 1) void fused12(
    const _Float16* __restrict__ a16, const _Float16* __restrict__ b16,
    const float* __restrict__ bih, const float* __restrict__ bhh,
    const float* __restrict__ Whh, float* __restrict__ out,
    unsigned int* __restrict__ cnt) {
    __shared__ __align__(16) unsigned char smem[32768];  // p1: Al+Bl; p2: himg

    const int tid  = threadIdx.x;
    const int bid  = blockIdx.x;
    const int wv   = tid >> 6;
    const int lane = tid & 63;
    const int n    = lane & 15;
    const int quad = lane >> 4;

    if (bid >= 64) {
        // ================= phase1 role: xp = a16 @ b16^T + bias =========
        _Float16* Al = (_Float16*)smem;             // [128][64]
        _Float16* Bl = (_Float16*)(smem + 16384);   // [128][64]
        const int p  = bid - 64;        // 0..1023, s-tile major
        const int st = p >> 8;          // 0..3
        const int r  = p & 255;
        const int bb = r >> 2;          // batch
        const int nt = r & 3;           // n-tile
        const int m0 = bb * 512 + st * 128;
        const int n0 = nt * 128;

        // staging: wave w covers rows [16w,16w+16) in 2 issues of 8 rows.
        const int srow = wv * 16 + (lane >> 3);
        const int scol = (lane & 7) * 8;
        const _Float16* agl = a16 + (size_t)(m0 + srow) * EE + scol;
        const _Float16* bgl = b16 + (size_t)(n0 + srow) * EE + scol;
        _Float16* al = Al + wv * 1024;
        _Float16* bl = Bl + wv * 1024;

        const int mw = wv >> 2;         // 0..1 (64-row half)
        const int nw = wv & 3;          // 0..3 (32-col quarter)

        f32x4 acc[4][2];
#pragma unroll
        for (int mb = 0; mb < 4; ++mb)
#pragma unroll
            for (int nb = 0; nb < 2; ++nb) acc[mb][nb] = (f32x4){0.f, 0.f, 0.f, 0.f};

        for (int kc = 0; kc < 8; ++kc) {
            gload16(agl + kc * 64,               al);
            gload16(agl + (size_t)8 * EE + kc * 64, al + 512);
            gload16(bgl + kc * 64,               bl);
            gload16(bgl + (size_t)8 * EE + kc * 64, bl + 512);
            __syncthreads();

#pragma unroll
            for (int kk = 0; kk < 2; ++kk) {
                f16x8 bfr[2];
#pragma unroll
                for (int nb = 0; nb < 2; ++nb)
                    bfr[nb] = *(const f16x8*)&Bl[(nw * 32 + nb * 16 + n) * 64 + kk * 32 + quad * 8];
#pragma unroll
                for (int mb = 0; mb < 4; ++mb) {
                    f16x8 afr = *(const f16x8*)&Al[(mw * 64 + mb * 16 + n) * 64 + kk * 32 + quad * 8];
#pragma unroll
                    for (int nb = 0; nb < 2; ++nb)
                        acc[mb][nb] = __builtin_amdgcn_mfma_f32_16x16x32_f16(
                            afr, bfr[nb], acc[mb][nb], 0, 0, 0);
                }
            }
            __syncthreads();
        }

        int   cc[2];
        float bv[2];
#pragma unroll
        for (int nb = 0; nb < 2; ++nb) {
            cc[nb] = n0 + nw * 32 + nb * 16 + n;
            bv[nb] = bih[cc[nb]] + bhh[cc[nb]];
        }
#pragma unroll
        for (int mb = 0; mb < 4; ++mb) {
            int rowg = m0 + mw * 64 + mb * 16 + quad * 4;
#pragma unroll
            for (int nb = 0; nb < 2; ++nb) {
#pragma unroll
                for (int i = 0; i < 4; ++i)
                    out[(size_t)(rowg + i) * HH + cc[nb]] = acc[mb][nb][i] + bv[nb];
            }
        }
        // completion: drain stores, then one release + count.
        __asm__ volatile("s_waitcnt vmcnt(0)" ::: "memory");
        __syncthreads();
        if (tid == 0) {
            __builtin_amdgcn_fence(__ATOMIC_RELEASE, "agent");
            __hip_atomic_fetch_add(cnt + st, 1u, __ATOMIC_RELAXED,
                                   __HIP_MEMORY_SCOPE_AGENT);
        }
        return;
    }

    // ================= phase2 role (v3b recurrence, batch = bid) =========
    unsigned char* h0p = smem;          // ping-pong i8 h images (512 B each)
    unsigned char* h1p = smem + 512;
    const int b = bid;

    iv4 areg[4][8];
#pragma unroll
    for (int mb = 0; mb < 4; ++mb) {
        const float* wr = Whh + (size_t)(wv * 64 + mb * 16 + n) * HH + quad * 16;
#pragma unroll
        for (int j = 0; j < 8; ++j) {
            int kb = (j < 7) ? ((wv + 1 + j) & 7) : wv;
            const float4* ptr = (const float4*)(wr + kb * 64);
            iv4 v;
            v[0] = packw4(ptr[0]);
            v[1] = packw4(ptr[1]);
            v[2] = packw4(ptr[2]);
            v[3] = packw4(ptr[3]);
            areg[mb][j] = v;
        }
    }
    if (tid < 64) ((u64*)h0p)[tid] = 0ull;   // h0 = 0
    __syncthreads();

    const int  ilo = n & 1;
    const int  ihi = (n >> 1) & 1;
    const bool sb0 = ((n >> 2) & 1) != 0;
    const bool sb1 = ((n >> 3) & 1) != 0;
    const int  row = wv * 64 + ((n >> 2) & 3) * 16 + quad * 4 + (n & 3);
    float* obase = out + (size_t)b * (SS * HH) + row;

    int koff[7];
#pragma unroll
    for (int j = 0; j < 7; ++j) koff[j] = ((wv + 1 + j) & 7) * 64 + quad * 16;
    const int oown = wv * 64 + quad * 16;

    const float inv2 = (2.0f * 1.4426950408889634f) / (SW * 127.0f);
    const float K2   = 2.0f * 1.4426950408889634f;

    iv4 acc0 = (iv4){0,0,0,0}, acc1 = (iv4){0,0,0,0};
    iv4 acc2 = (iv4){0,0,0,0}, acc3 = (iv4){0,0,0,0};

    wait_tile(cnt, 256u);               // xp tile 0 ready
    float xp2_c = obase[0] * K2;
    float xp2_n = obase[HH] * K2;
    float hl = 0.f;

#define RNN_STEP(T, HBR, HNX)                                                  \
    {                                                                          \
        if ((((T) + 2) & 127) == 0 && ((T) + 2) < SS)                          \
            wait_tile(cnt + (((T) + 2) >> 7), 256u);                           \
        float xp_f = obase[(size_t)((T) + 2) * HH];                            \
        _Pragma("unroll")                                                      \
        for (int j = 0; j < 7; ++j) {                                          \
            iv4 bfr = *(const iv4*)((HBR) + koff[j]);                          \
            acc0 = __builtin_amdgcn_mfma_i32_16x16x64_i8(areg[0][j], bfr, acc0, 0, 0, 0); \
            acc1 = __builtin_amdgcn_mfma_i32_16x16x64_i8(areg[1][j], bfr, acc1, 0, 0, 0); \
            acc2 = __builtin_amdgcn_mfma_i32_16x16x64_i8(areg[2][j], bfr, acc2, 0, 0, 0); \
            acc3 = __builtin_amdgcn_mfma_i32_16x16x64_i8(areg[3][j], bfr, acc3, 0, 0, 0); \
        }                                                                      \
        iv4 sa = sb0 ? acc1 : acc0;                                            \
        iv4 sc = sb0 ? acc3 : acc2;                                            \
        iv4 s  = sb1 ? sc : sa;                                                \
        int zA = ilo ? s[1] : s[0];                                            \
        int zB = ilo ? s[3] : s[2];                                            \
        int z  = ihi ? zB : zA;                                                \
        float u  = fmaf((float)z, inv2, xp2_c);                                \
        float ex;                                                              \
        __asm__("v_exp_f32 %0, %1" : "=v"(ex) : "v"(u));                       \
        float rr = __builtin_amdgcn_rcpf(ex + 1.0f);                           \
        int   q  = (int)rintf(fmaf(rr, -254.0f, 127.0f));                      \
        *(char*)((HNX) + row) = (char)q;                                       \
        iv4 bown = *(const iv4*)((HNX) + oown);                                \
        acc0 = __builtin_amdgcn_mfma_i32_16x16x64_i8(areg[0][7], bown, (iv4){0,0,0,0}, 0, 0, 0); \
        acc1 = __builtin_amdgcn_mfma_i32_16x16x64_i8(areg[1][7], bown, (iv4){0,0,0,0}, 0, 0, 0); \
        acc2 = __builtin_amdgcn_mfma_i32_16x16x64_i8(areg[2][7], bown, (iv4){0,0,0,0}, 0, 0, 0); \
        acc3 = __builtin_amdgcn_mfma_i32_16x16x64_i8(areg[3][7], bown, (iv4){0,0,0,0}, 0, 0, 0); \
        float h = fmaf(rr, -2.0f, 1.0f);                                       \
        obase[(size_t)(T) * HH] = h;                                           \
        hl = h;                                                                \
        __builtin_amdgcn_sched_barrier(0);                                     \
        __asm__ volatile("s_waitcnt lgkmcnt(0)\n\ts_barrier" ::: "memory");    \
        xp2_c = xp2_n; xp2_n = xp_f * K2;                                      \
    }

    for (int t = 0; t < SS; t += 2) {
        RNN_STEP(t,     h0p, h1p);
        RNN_STEP(t + 1, h1p, h0p);
    }
#undef RNN_STEP

    out[BSH + (size_t)b * HH + row] = hl;
}

// ---------------- Fallbacks (no/small workspace): f32 phase1 + solo phase2.
__global__ __launch_bounds__(256, 3) void phase1(
    const int* __restrict__ idx, const float* __restrict__ emb,
    const float* __restrict__ Wih, const float* __restrict__ bih,
    const float* __restrict__ bhh, float* __restrict__ out) {
    __shared__ __align__(16) _Float16 Al[128 * 72];
    __shared__ __align__(16) _Float16 Bl[128 * 72];

    const int tid  = threadIdx.x;
    const int m0   = (blockIdx.x >> 2) * 128;
    const int n0   = (blockIdx.x & 3) * 128;
    const int wv   = tid >> 6;
    const int lane = tid & 63;
    const int n    = lane & 15;
    const int quad = lane >> 4;
    const int mw   = wv >> 1;
    const int nw   = wv & 1;

    const int sr = tid >> 1;
    const int kh = (tid & 1) * 32;
    const int rowidx = idx[m0 + sr];
    const float* ap = emb + (size_t)rowidx * EE + kh;
    const float* bp = Wih + (size_t)(n0 + sr) * EE + kh;

    f32x4 acc[4][4];
#pragma unroll
    for (int a = 0; a < 4; ++a)
#pragma unroll
        for (int c = 0; c < 4; ++c) acc[a][c] = (f32x4){0.f, 0.f, 0.f, 0.f};

    for (int kc = 0; kc < 8; ++kc) {
#pragma unroll
        for (int q = 0; q < 4; ++q) {
            float4 u = *(const float4*)(ap + kc * 64 + q * 8);
            float4 v = *(const float4*)(ap + kc * 64 + q * 8 + 4);
            *(f16x8*)&Al[sr * 72 + kh + q * 8] = pack8(u, v);
        }
#pragma unroll
        for (int q = 0; q < 4; ++q) {
            float4 u = *(const float4*)(bp + kc * 64 + q * 8);
            float4 v = *(const float4*)(bp + kc * 64 + q * 8 + 4);
            *(f16x8*)&Bl[sr * 72 + kh + q * 8] = pack8(u, v);
        }
        __syncthreads();

#pragma unroll
        for (int kk = 0; kk < 2; ++kk) {
            f16x8 bfr[4];
#pragma unroll
            for (int nb = 0; nb < 4; ++nb)
                bfr[nb] = *(const f16x8*)&Bl[(nw * 64 + nb * 16 + n) * 72 + kk * 32 + quad * 8];
#pragma unroll
            for (int mb = 0; mb < 4; ++mb) {
                f16x8 afr = *(const f16x8*)&Al[(mw * 64 + mb * 16 + n) * 72 + kk * 32 + quad * 8];
#pragma unroll
                for (int nb = 0; nb < 4; ++nb)
                    acc[mb][nb] = __builtin_amdgcn_mfma_f32_16x16x32_f16(
                        afr, bfr[nb], acc[mb][nb], 0, 0, 0);
            }
        }
        __syncthreads();
    }

    int   cc[4];
    float bv[4];
#pragma unroll
    for (int nb = 0; nb < 4; ++nb) {
        cc[nb] = n0 + nw * 64 + nb * 16 + n;
        bv[nb] = bih[cc[nb]] + bhh[cc[nb]];
    }
#pragma unroll
    for (int mb = 0; mb < 4; ++mb) {
        int rowg = m0 + mw * 64 + mb * 16 + quad * 4;
#pragma unroll
        for (int nb = 0; nb < 4; ++nb) {
#pragma unroll
            for (int i = 0; i < 4; ++i)
                out[(size_t)(rowg + i) * HH + cc[nb]] = acc[mb][nb][i] + bv[nb];
        }
    }
}

__global__ __launch_bounds__(512, 1) void phase2(
    const float* __restrict__ Whh, float* __restrict__ out) {
    __shared__ __align__(16) unsigned char himg[2][512];

    const int tid  = threadIdx.x;
    const int b    = blockIdx.x;
    const int wv   = tid >> 6;
    const int lane = tid & 63;
    const int n    = lane & 15;
    const int quad = lane >> 4;

    iv4 areg[4][8];
#pragma unroll
    for (int mb = 0; mb < 4; ++mb) {
        const float* wr = Whh + (size_t)(wv * 64 + mb * 16 + n) * HH + quad * 16;
#pragma unroll
        for (int j = 0; j < 8; ++j) {
            int kb = (j < 7) ? ((wv + 1 + j) & 7) : wv;
            const float4* p = (const float4*)(wr + kb * 64);
            iv4 v;
            v[0] = packw4(p[0]);
            v[1] = packw4(p[1]);
            v[2] = packw4(p[2]);
            v[3] = packw4(p[3]);
            areg[mb][j] = v;
        }
    }
    if (tid < 64) ((u64*)himg[0])[tid] = 0ull;
    __syncthreads();

    const int  ilo = n & 1;
    const int  ihi = (n >> 1) & 1;
    const bool sb0 = ((n >> 2) & 1) != 0;
    const bool sb1 = ((n >> 3) & 1) != 0;
    const int  row = wv * 64 + ((n >> 2) & 3) * 16 + quad * 4 + (n & 3);
    float* obase = out + (size_t)b * (SS * HH) + row;

    int koff[7];
#pragma unroll
    for (int j = 0; j < 7; ++j) koff[j] = ((wv + 1 + j) & 7) * 64 + quad * 16;
    const int oown = wv * 64 + quad * 16;

    const float inv2 = (2.0f * 1.4426950408889634f) / (SW * 127.0f);
    const float K2   = 2.0f * 1.4426950408889634f;

    iv4 acc0 = (iv4){0,0,0,0}, acc1 = (iv4){0,0,0,0};
    iv4 acc2 = (iv4){0,0,0,0}, acc3 = (iv4){0,0,0,0};

    float xp2_c = obase[0] * K2;
    float xp2_n = obase[HH] * K2;
    float hl = 0.f;
    unsigned char* h0p = himg[0];
    unsigned char* h1p = himg[1];

#define RNN_STEP(T, HBR, HNX)                                                  \
    {                                                                          \
        float xp_f = obase[(size_t)((T) + 2) * HH];                            \
        _Pragma("unroll")                                                      \
        for (int j = 0; j < 7; ++j) {                                          \
            iv4 bfr = *(const iv4*)((HBR) + koff[j]);                          \
            acc0 = __builtin_amdgcn_mfma_i32_16x16x64_i8(areg[0][j], bfr, acc0, 0, 0, 0); \
            acc1 = __builtin_amdgcn_mfma_i32_16x16x64_i8(areg[1][j], bfr, acc1, 0, 0, 0); \
            acc2 = __builtin_amdgcn_mfma_i32_16x16x64_i8(areg[2][j], bfr, acc2, 0, 0, 0); \
            acc3 = __builtin_amdgcn_mfma_i32_16x16x64_i8(areg[3][j], bfr, acc3, 0, 0, 0); \
        }                                                                      \
        iv4 sa = sb0 ? acc1 : acc0;                                            \
        iv4 sc = sb0 ? acc3 : acc2;                                            \
        iv4 s  = sb1 ? sc : sa;                                                \
        int zA = ilo ? s[1] : s[0];                                            \
        int zB = ilo ? s[3] : s[2];                                            \
        int z  = ihi ? zB : zA;                                                \
        float u  = fmaf((float)z, inv2, xp2_c);                                \
        float ex;                                                              \
        __asm__("v_exp_f32 %0, %1" : "=v"(ex) : "v"(u));                       \
        float rr = __builtin_amdgcn_rcpf(ex + 1.0f);                           \
        int   q  = (int)rintf(fmaf(rr, -254.0f, 127.0f));                      \
        *(char*)((HNX) + row) = (char)q;                                       \
        iv4 bown = *(const iv4*)((HNX) + oown);                                \
        acc0 = __builtin_amdgcn_mfma_i32_16x16x64_i8(areg[0][7], bown, (iv4){0,0,0,0}, 0, 0, 0); \
        acc1 = __builtin_amdgcn_mfma_i32_16x16x64_i8(areg[1][7], bown, (iv4){0,0,0,0}, 0, 0, 0); \
        acc2 = __builtin_amdgcn_mfma_i32_16x16x64_i8(areg[2][7], bown, (iv4){0,0,0,0}, 0, 0, 0); \
        acc3 = __builtin_amdgcn_mfma_i32_16x16x64_i8(areg[3][7], bown, (iv4){0,0,0,0}, 0, 0, 0); \
        float h = fmaf(rr, -2.0f, 1.0f);                                       \
        obase[(size_t)(T) * HH] = h;                                           \
        hl = h;                                                                \
        __builtin_amdgcn_sched_barrier(0);                                     \
        __asm__ volatile("s_waitcnt lgkmcnt(0)\n\ts_barrier" ::: "memory");    \
        xp2_c = xp2_n; xp2_n = xp_f * K2;                                      \
    }

    for (int t = 0; t < SS; t += 2) {
        RNN_STEP(t,     h0p, h1p);
        RNN_STEP(t + 1, h1p, h0p);
    }
#undef RNN_STEP

    out[BSH + (size_t)b * HH + row] = hl;
}

extern "C" void kernel_launch(void* const* d_in, const int* in_sizes, int n_in,
                              void* d_out, int out_size, void* d_ws, size_t ws_size,
                              hipStream_t stream) {
    const int*   idx = (const int*)d_in[0];
    const float* emb = (const float*)d_in[1];
    const float* Wih = (const float*)d_in[2];
    const float* Whh = (const float*)d_in[3];
    const float* bih = (const float*)d_in[4];
    const float* bhh = (const float*)d_in[5];
    float* out = (float*)d_out;

    const size_t needA = (size_t)BB * SS * EE * sizeof(_Float16);  // 32 MB
    const size_t needB = (size_t)HH * EE * sizeof(_Float16);       // 0.5 MB
    const size_t CNTOFF = needA + needB;                           // counters
    const size_t needT = CNTOFF + 4 * sizeof(unsigned int);

    if (d_ws && ws_size >= needT) {
        _Float16* a16 = (_Float16*)d_ws;
        _Float16* b16 = (_Float16*)((char*)d_ws + needA);
        unsigned int* cnt = (unsigned int*)((char*)d_ws + CNTOFF);
        hipMemsetAsync(cnt, 0, 4 * sizeof(unsigned int), stream);
        prep<<<dim3(8192 + 128), dim3(256), 0, stream>>>(idx, emb, Wih, a16, b16);
        fused12<<<dim3(64 + 1024), dim3(512), 0, stream>>>(
            a16, b16, bih, bhh, Whh, out, cnt);
    } else {
        phase1<<<dim3(1024), dim3(256), 0, stream>>>(idx, emb, Wih, bih, bhh, out);
        phase2<<<dim3(64), dim3(512), 0, stream>>>(Whh, out);
    }
}

// Round 7
// 548.735 us; speedup vs baseline: 1.0077x; 1.0077x over previous
//
#include <hip/hip_runtime.h>
#include <cstdint>

#define BB 64
#define SS 512
#define HH 512
#define EE 512
#define BSH (BB*SS*HH)

typedef _Float16 f16x8 __attribute__((ext_vector_type(8)));
typedef float    f32x4 __attribute__((ext_vector_type(4)));
typedef int      iv4   __attribute__((ext_vector_type(4)));
typedef unsigned long long u64;

__device__ __forceinline__ f16x8 pack8(float4 u, float4 v) {
    f16x8 h;
    h[0] = (_Float16)u.x; h[1] = (_Float16)u.y;
    h[2] = (_Float16)u.z; h[3] = (_Float16)u.w;
    h[4] = (_Float16)v.x; h[5] = (_Float16)v.y;
    h[6] = (_Float16)v.z; h[7] = (_Float16)v.w;
    return h;
}

// W scale: |W| <= 1/sqrt(512); map to [-127,127]
#define SW (127.0f * 22.627416997969522f)

__device__ __forceinline__ int quanw(float x) {
    return (int)rintf(fminf(fmaxf(x * SW, -127.0f), 127.0f));
}
__device__ __forceinline__ int packw4(float4 f) {
    int q0 = quanw(f.x), q1 = quanw(f.y), q2 = quanw(f.z), q3 = quanw(f.w);
    return (q0 & 255) | ((q1 & 255) << 8) | ((q2 & 255) << 16) | (q3 << 24);
}

// XOR bank swizzle for [128][64]-f16 LDS tiles: chunk(16B) index ^= row&7.
// Applied on BOTH ds_write (reg staging) and ds_read -> 16-way conflict
// drops to the b128 floor. off in f16 units (multiple of 8).
#define SWZ(row, off) ((row) * 64 + ((off) ^ (((row) & 7) << 3)))

// poll a monotone tile counter (relaxed), then one acquire fence.
// 4 polls per phase2 WG total -- NOT per-step (R4 lesson).
__device__ __forceinline__ void wait_tile(const unsigned int* c, unsigned int tgt) {
    while (__hip_atomic_load(c, __ATOMIC_RELAXED, __HIP_MEMORY_SCOPE_AGENT) < tgt) {
        __builtin_amdgcn_s_sleep(2);
    }
    __builtin_amdgcn_fence(__ATOMIC_ACQUIRE, "agent");
}

// ---------------- FUSED kernel.
// bids 0..63   : phase2 role, one batch each (dispatched first -> own CUs).
// bids 64..1087: phase1 role, one 128x128 xp tile, s-tile-major:
//                p = (st*64 + bb)*4 + nt. In-kernel f32->f16 (pack8) staging
//                (no prep pass; emb/Wih re-reads are L3-resident).
// Readiness: per-(st,batch) counter cnt[st*64+bb], target 4 (its 4 n-tiles).
// phase2 WG b polls only its own column -> tile-0 stall ~= 4 tiles, not 256.
// One-way dependency, phase1 never waits -> deadlock-free.
__global__ __launch_bounds__(512, 1) void fused12(
    const int* __restrict__ idx, const float* __restrict__ emb,
    const float* __restrict__ Wih,
    const float* __restrict__ bih, const float* __restrict__ bhh,
    const float* __restrict__ Whh, float* __restrict__ out,
    unsigned int* __restrict__ cnt) {
    __shared__ __align__(16) unsigned char smem[32768];  // p1: Al+Bl; p2: himg

    const int tid  = threadIdx.x;
    const int bid  = blockIdx.x;
    const int wv   = tid >> 6;
    const int lane = tid & 63;
    const int n    = lane & 15;
    const int quad = lane >> 4;

    if (bid >= 64) {
        // ================= phase1 role: xp = emb[idx] @ Wih^T + bias ======
        _Float16* Al = (_Float16*)smem;             // [128][64] swizzled
        _Float16* Bl = (_Float16*)(smem + 16384);   // [128][64] swizzled
        const int p  = bid - 64;        // 0..1023
        const int st = p >> 8;          // s-tile 0..3
        const int bb = (p >> 2) & 63;   // batch
        const int nt = p & 3;           // n-tile
        const int m0 = bb * 512 + st * 128;
        const int n0 = nt * 128;

        // staging: thread covers row tid>>2, f32 cols (tid&3)*16..+16 of the
        // current kc window -> 2 swizzled 16B LDS chunks (A and B each).
        const int arow = tid >> 2;
        const int coff = (tid & 3) * 16;
        const int rowidx = idx[m0 + arow];
        const float* ap = emb + (size_t)rowidx * EE + coff;
        const float* bp = Wih + (size_t)(n0 + arow) * EE + coff;
        const int woff0 = SWZ(arow, coff);       // coff is mult of 16 (chunks)
        const int woff1 = SWZ(arow, coff + 8);

        const int mw = wv >> 2;         // 0..1 (64-row half)
        const int nw = wv & 3;          // 0..3 (32-col quarter)

        f32x4 acc[4][2];
#pragma unroll
        for (int mb = 0; mb < 4; ++mb)
#pragma unroll
            for (int nb = 0; nb < 2; ++nb) acc[mb][nb] = (f32x4){0.f, 0.f, 0.f, 0.f};

        for (int kc = 0; kc < 8; ++kc) {
            {
                const float4* la = (const float4*)(ap + kc * 64);
                const float4* lb = (const float4*)(bp + kc * 64);
                float4 a0 = la[0], a1 = la[1], a2 = la[2], a3 = la[3];
                float4 b0 = lb[0], b1 = lb[1], b2 = lb[2], b3 = lb[3];
                *(f16x8*)&Al[woff0] = pack8(a0, a1);
                *(f16x8*)&Al[woff1] = pack8(a2, a3);
                *(f16x8*)&Bl[woff0] = pack8(b0, b1);
                *(f16x8*)&Bl[woff1] = pack8(b2, b3);
            }
            __syncthreads();

#pragma unroll
            for (int kk = 0; kk < 2; ++kk) {
                f16x8 bfr[2];
#pragma unroll
                for (int nb = 0; nb < 2; ++nb)
                    bfr[nb] = *(const f16x8*)&Bl[SWZ(nw * 32 + nb * 16 + n, kk * 32 + quad * 8)];
#pragma unroll
                for (int mb = 0; mb < 4; ++mb) {
                    f16x8 afr = *(const f16x8*)&Al[SWZ(mw * 64 + mb * 16 + n, kk * 32 + quad * 8)];
#pragma unroll
                    for (int nb = 0; nb < 2; ++nb)
                        acc[mb][nb] = __builtin_amdgcn_mfma_f32_16x16x32_f16(
                            afr, bfr[nb], acc[mb][nb], 0, 0, 0);
                }
            }
            __syncthreads();
        }

        int   cc[2];
        float bv[2];
#pragma unroll
        for (int nb = 0; nb < 2; ++nb) {
            cc[nb] = n0 + nw * 32 + nb * 16 + n;
            bv[nb] = bih[cc[nb]] + bhh[cc[nb]];
        }
#pragma unroll
        for (int mb = 0; mb < 4; ++mb) {
            int rowg = m0 + mw * 64 + mb * 16 + quad * 4;
#pragma unroll
            for (int nb = 0; nb < 2; ++nb) {
#pragma unroll
                for (int i = 0; i < 4; ++i)
                    out[(size_t)(rowg + i) * HH + cc[nb]] = acc[mb][nb][i] + bv[nb];
            }
        }
        // completion: drain own stores, barrier, one release + count.
        __asm__ volatile("s_waitcnt vmcnt(0)" ::: "memory");
        __syncthreads();
        if (tid == 0) {
            __builtin_amdgcn_fence(__ATOMIC_RELEASE, "agent");
            __hip_atomic_fetch_add(cnt + st * 64 + bb, 1u, __ATOMIC_RELAXED,
                                   __HIP_MEMORY_SCOPE_AGENT);
        }
        return;
    }

    // ================= phase2 role (v3b recurrence, batch = bid) =========
    unsigned char* h0p = smem;          // ping-pong i8 h images (512 B each)
    unsigned char* h1p = smem + 512;
    const int b = bid;

    iv4 areg[4][8];
#pragma unroll
    for (int mb = 0; mb < 4; ++mb) {
        const float* wr = Whh + (size_t)(wv * 64 + mb * 16 + n) * HH + quad * 16;
#pragma unroll
        for (int j = 0; j < 8; ++j) {
            int kb = (j < 7) ? ((wv + 1 + j) & 7) : wv;
            const float4* ptr = (const float4*)(wr + kb * 64);
            iv4 v;
            v[0] = packw4(ptr[0]);
            v[1] = packw4(ptr[1]);
            v[2] = packw4(ptr[2]);
            v[3] = packw4(ptr[3]);
            areg[mb][j] = v;
        }
    }
    if (tid < 64) ((u64*)h0p)[tid] = 0ull;   // h0 = 0
    __syncthreads();

    const int  ilo = n & 1;
    const int  ihi = (n >> 1) & 1;
    const bool sb0 = ((n >> 2) & 1) != 0;
    const bool sb1 = ((n >> 3) & 1) != 0;
    const int  row = wv * 64 + ((n >> 2) & 3) * 16 + quad * 4 + (n & 3);
    float* obase = out + (size_t)b * (SS * HH) + row;

    int koff[7];
#pragma unroll
    for (int j = 0; j < 7; ++j) koff[j] = ((wv + 1 + j) & 7) * 64 + quad * 16;
    const int oown = wv * 64 + quad * 16;

    const float inv2 = (2.0f * 1.4426950408889634f) / (SW * 127.0f);
    const float K2   = 2.0f * 1.4426950408889634f;

    iv4 acc0 = (iv4){0,0,0,0}, acc1 = (iv4){0,0,0,0};
    iv4 acc2 = (iv4){0,0,0,0}, acc3 = (iv4){0,0,0,0};

    wait_tile(cnt + b, 4u);             // xp tile (st=0, this batch) ready
    float xp2_c = obase[0] * K2;
    float xp2_n = obase[HH] * K2;
    float hl = 0.f;

#define RNN_STEP(T, HBR, HNX)                                                  \
    {                                                                          \
        if ((((T) + 2) & 127) == 0 && ((T) + 2) < SS)                          \
            wait_tile(cnt + ((((T) + 2) >> 7) * 64 + b), 4u);                  \
        float xp_f = obase[(size_t)((T) + 2) * HH];                            \
        _Pragma("unroll")                                                      \
        for (int j = 0; j < 7; ++j) {                                          \
            iv4 bfr = *(const iv4*)((HBR) + koff[j]);                          \
            acc0 = __builtin_amdgcn_mfma_i32_16x16x64_i8(areg[0][j], bfr, acc0, 0, 0, 0); \
            acc1 = __builtin_amdgcn_mfma_i32_16x16x64_i8(areg[1][j], bfr, acc1, 0, 0, 0); \
            acc2 = __builtin_amdgcn_mfma_i32_16x16x64_i8(areg[2][j], bfr, acc2, 0, 0, 0); \
            acc3 = __builtin_amdgcn_mfma_i32_16x16x64_i8(areg[3][j], bfr, acc3, 0, 0, 0); \
        }                                                                      \
        iv4 sa = sb0 ? acc1 : acc0;                                            \
        iv4 sc = sb0 ? acc3 : acc2;                                            \
        iv4 s  = sb1 ? sc : sa;                                                \
        int zA = ilo ? s[1] : s[0];                                            \
        int zB = ilo ? s[3] : s[2];                                            \
        int z  = ihi ? zB : zA;                                                \
        float u  = fmaf((float)z, inv2, xp2_c);                                \
        float ex;                                                              \
        __asm__("v_exp_f32 %0, %1" : "=v"(ex) : "v"(u));                       \
        float rr = __builtin_amdgcn_rcpf(ex + 1.0f);                           \
        int   q  = (int)rintf(fmaf(rr, -254.0f, 127.0f));                      \
        *(char*)((HNX) + row) = (char)q;                                       \
        iv4 bown = *(const iv4*)((HNX) + oown);                                \
        acc0 = __builtin_amdgcn_mfma_i32_16x16x64_i8(areg[0][7], bown, (iv4){0,0,0,0}, 0, 0, 0); \
        acc1 = __builtin_amdgcn_mfma_i32_16x16x64_i8(areg[1][7], bown, (iv4){0,0,0,0}, 0, 0, 0); \
        acc2 = __builtin_amdgcn_mfma_i32_16x16x64_i8(areg[2][7], bown, (iv4){0,0,0,0}, 0, 0, 0); \
        acc3 = __builtin_amdgcn_mfma_i32_16x16x64_i8(areg[3][7], bown, (iv4){0,0,0,0}, 0, 0, 0); \
        float h = fmaf(rr, -2.0f, 1.0f);                                       \
        obase[(size_t)(T) * HH] = h;                                           \
        hl = h;                                                                \
        __builtin_amdgcn_sched_barrier(0);                                     \
        __asm__ volatile("s_waitcnt lgkmcnt(0)\n\ts_barrier" ::: "memory");    \
        xp2_c = xp2_n; xp2_n = xp_f * K2;                                      \
    }

    for (int t = 0; t < SS; t += 2) {
        RNN_STEP(t,     h0p, h1p);
        RNN_STEP(t + 1, h1p, h0p);
    }
#undef RNN_STEP

    out[BSH + (size_t)b * HH + row] = hl;
}

// ---------------- Fallbacks (no workspace): serial f32 phase1 + solo phase2.
__global__ __launch_bounds__(256, 3) void phase1(
    const int* __restrict__ idx, const float* __restrict__ emb,
    const float* __restrict__ Wih, const float* __restrict__ bih,
    const float* __restrict__ bhh, float* __restrict__ out) {
    __shared__ __align__(16) _Float16 Al[128 * 72];
    __shared__ __align__(16) _Float16 Bl[128 * 72];

    const int tid  = threadIdx.x;
    const int m0   = (blockIdx.x >> 2) * 128;
    const int n0   = (blockIdx.x & 3) * 128;
    const int wv   = tid >> 6;
    const int lane = tid & 63;
    const int n    = lane & 15;
    const int quad = lane >> 4;
    const int mw   = wv >> 1;
    const int nw   = wv & 1;

    const int sr = tid >> 1;
    const int kh = (tid & 1) * 32;
    const int rowidx = idx[m0 + sr];
    const float* ap = emb + (size_t)rowidx * EE + kh;
    const float* bp = Wih + (size_t)(n0 + sr) * EE + kh;

    f32x4 acc[4][4];
#pragma unroll
    for (int a = 0; a < 4; ++a)
#pragma unroll
        for (int c = 0; c < 4; ++c) acc[a][c] = (f32x4){0.f, 0.f, 0.f, 0.f};

    for (int kc = 0; kc < 8; ++kc) {
#pragma unroll
        for (int q = 0; q < 4; ++q) {
            float4 u = *(const float4*)(ap + kc * 64 + q * 8);
            float4 v = *(const float4*)(ap + kc * 64 + q * 8 + 4);
            *(f16x8*)&Al[sr * 72 + kh + q * 8] = pack8(u, v);
        }
#pragma unroll
        for (int q = 0; q < 4; ++q) {
            float4 u = *(const float4*)(bp + kc * 64 + q * 8);
            float4 v = *(const float4*)(bp + kc * 64 + q * 8 + 4);
            *(f16x8*)&Bl[sr * 72 + kh + q * 8] = pack8(u, v);
        }
        __syncthreads();

#pragma unroll
        for (int kk = 0; kk < 2; ++kk) {
            f16x8 bfr[4];
#pragma unroll
            for (int nb = 0; nb < 4; ++nb)
                bfr[nb] = *(const f16x8*)&Bl[(nw * 64 + nb * 16 + n) * 72 + kk * 32 + quad * 8];
#pragma unroll
            for (int mb = 0; mb < 4; ++mb) {
                f16x8 afr = *(const f16x8*)&Al[(mw * 64 + mb * 16 + n) * 72 + kk * 32 + quad * 8];
#pragma unroll
                for (int nb = 0; nb < 4; ++nb)
                    acc[mb][nb] = __builtin_amdgcn_mfma_f32_16x16x32_f16(
                        afr, bfr[nb], acc[mb][nb], 0, 0, 0);
            }
        }
        __syncthreads();
    }

    int   cc[4];
    float bv[4];
#pragma unroll
    for (int nb = 0; nb < 4; ++nb) {
        cc[nb] = n0 + nw * 64 + nb * 16 + n;
        bv[nb] = bih[cc[nb]] + bhh[cc[nb]];
    }
#pragma unroll
    for (int mb = 0; mb < 4; ++mb) {
        int rowg = m0 + mw * 64 + mb * 16 + quad * 4;
#pragma unroll
        for (int nb = 0; nb < 4; ++nb) {
#pragma unroll
            for (int i = 0; i < 4; ++i)
                out[(size_t)(rowg + i) * HH + cc[nb]] = acc[mb][nb][i] + bv[nb];
        }
    }
}

__global__ __launch_bounds__(512, 1) void phase2(
    const float* __restrict__ Whh, float* __restrict__ out) {
    __shared__ __align__(16) unsigned char himg[2][512];

    const int tid  = threadIdx.x;
    const int b    = blockIdx.x;
    const int wv   = tid >> 6;
    const int lane = tid & 63;
    const int n    = lane & 15;
    const int quad = lane >> 4;

    iv4 areg[4][8];
#pragma unroll
    for (int mb = 0; mb < 4; ++mb) {
        const float* wr = Whh + (size_t)(wv * 64 + mb * 16 + n) * HH + quad * 16;
#pragma unroll
        for (int j = 0; j < 8; ++j) {
            int kb = (j < 7) ? ((wv + 1 + j) & 7) : wv;
            const float4* p = (const float4*)(wr + kb * 64);
            iv4 v;
            v[0] = packw4(p[0]);
            v[1] = packw4(p[1]);
            v[2] = packw4(p[2]);
            v[3] = packw4(p[3]);
            areg[mb][j] = v;
        }
    }
    if (tid < 64) ((u64*)himg[0])[tid] = 0ull;
    __syncthreads();

    const int  ilo = n & 1;
    const int  ihi = (n >> 1) & 1;
    const bool sb0 = ((n >> 2) & 1) != 0;
    const bool sb1 = ((n >> 3) & 1) != 0;
    const int  row = wv * 64 + ((n >> 2) & 3) * 16 + quad * 4 + (n & 3);
    float* obase = out + (size_t)b * (SS * HH) + row;

    int koff[7];
#pragma unroll
    for (int j = 0; j < 7; ++j) koff[j] = ((wv + 1 + j) & 7) * 64 + quad * 16;
    const int oown = wv * 64 + quad * 16;

    const float inv2 = (2.0f * 1.4426950408889634f) / (SW * 127.0f);
    const float K2   = 2.0f * 1.4426950408889634f;

    iv4 acc0 = (iv4){0,0,0,0}, acc1 = (iv4){0,0,0,0};
    iv4 acc2 = (iv4){0,0,0,0}, acc3 = (iv4){0,0,0,0};

    float xp2_c = obase[0] * K2;
    float xp2_n = obase[HH] * K2;
    float hl = 0.f;
    unsigned char* h0p = himg[0];
    unsigned char* h1p = himg[1];

#define RNN_STEP(T, HBR, HNX)                                                  \
    {                                                                          \
        float xp_f = obase[(size_t)((T) + 2) * HH];                            \
        _Pragma("unroll")                                                      \
        for (int j = 0; j < 7; ++j) {                                          \
            iv4 bfr = *(const iv4*)((HBR) + koff[j]);                          \
            acc0 = __builtin_amdgcn_mfma_i32_16x16x64_i8(areg[0][j], bfr, acc0, 0, 0, 0); \
            acc1 = __builtin_amdgcn_mfma_i32_16x16x64_i8(areg[1][j], bfr, acc1, 0, 0, 0); \
            acc2 = __builtin_amdgcn_mfma_i32_16x16x64_i8(areg[2][j], bfr, acc2, 0, 0, 0); \
            acc3 = __builtin_amdgcn_mfma_i32_16x16x64_i8(areg[3][j], bfr, acc3, 0, 0, 0); \
        }                                                                      \
        iv4 sa = sb0 ? acc1 : acc0;                                            \
        iv4 sc = sb0 ? acc3 : acc2;                                            \
        iv4 s  = sb1 ? sc : sa;                                                \
        int zA = ilo ? s[1] : s[0];                                            \
        int zB = ilo ? s[3] : s[2];                                            \
        int z  = ihi ? zB : zA;                                                \
        float u  = fmaf((float)z, inv2, xp2_c);                                \
        float ex;                                                              \
        __asm__("v_exp_f32 %0, %1" : "=v"(ex) : "v"(u));                       \
        float rr = __builtin_amdgcn_rcpf(ex + 1.0f);                           \
        int   q  = (int)rintf(fmaf(rr, -254.0f, 127.0f));                      \
        *(char*)((HNX) + row) = (char)q;                                       \
        iv4 bown = *(const iv4*)((HNX) + oown);                                \
        acc0 = __builtin_amdgcn_mfma_i32_16x16x64_i8(areg[0][7], bown, (iv4){0,0,0,0}, 0, 0, 0); \
        acc1 = __builtin_amdgcn_mfma_i32_16x16x64_i8(areg[1][7], bown, (iv4){0,0,0,0}, 0, 0, 0); \
        acc2 = __builtin_amdgcn_mfma_i32_16x16x64_i8(areg[2][7], bown, (iv4){0,0,0,0}, 0, 0, 0); \
        acc3 = __builtin_amdgcn_mfma_i32_16x16x64_i8(areg[3][7], bown, (iv4){0,0,0,0}, 0, 0, 0); \
        float h = fmaf(rr, -2.0f, 1.0f);                                       \
        obase[(size_t)(T) * HH] = h;                                           \
        hl = h;                                                                \
        __builtin_amdgcn_sched_barrier(0);                                     \
        __asm__ volatile("s_waitcnt lgkmcnt(0)\n\ts_barrier" ::: "memory");    \
        xp2_c = xp2_n; xp2_n = xp_f * K2;                                      \
    }

    for (int t = 0; t < SS; t += 2) {
        RNN_STEP(t,     h0p, h1p);
        RNN_STEP(t + 1, h1p, h0p);
    }
#undef RNN_STEP

    out[BSH + (size_t)b * HH + row] = hl;
}

extern "C" void kernel_launch(void* const* d_in, const int* in_sizes, int n_in,
                              void* d_out, int out_size, void* d_ws, size_t ws_size,
                              hipStream_t stream) {
    const int*   idx = (const int*)d_in[0];
    const float* emb = (const float*)d_in[1];
    const float* Wih = (const float*)d_in[2];
    const float* Whh = (const float*)d_in[3];
    const float* bih = (const float*)d_in[4];
    const float* bhh = (const float*)d_in[5];
    float* out = (float*)d_out;

    const size_t CNTBYTES = 256 * sizeof(unsigned int);  // (st,batch) counters

    if (d_ws && ws_size >= CNTBYTES) {
        unsigned int* cnt = (unsigned int*)d_ws;
        hipMemsetAsync(cnt, 0, CNTBYTES, stream);
        fused12<<<dim3(64 + 1024), dim3(512), 0, stream>>>(
            idx, emb, Wih, bih, bhh, Whh, out, cnt);
    } else {
        phase1<<<dim3(1024), dim3(256), 0, stream>>>(idx, emb, Wih, bih, bhh, out);
        phase2<<<dim3(64), dim3(512), 0, stream>>>(Whh, out);
    }
}

// Round 8
// 535.875 us; speedup vs baseline: 1.0319x; 1.0240x over previous
//
#include <hip/hip_runtime.h>
#include <cstdint>

#define BB 64
#define SS 512
#define HH 512
#define EE 512
#define BSH (BB*SS*HH)

typedef _Float16 f16x8 __attribute__((ext_vector_type(8)));
typedef float    f32x4 __attribute__((ext_vector_type(4)));
typedef int      iv4   __attribute__((ext_vector_type(4)));
typedef unsigned long long u64;

__device__ __forceinline__ f16x8 pack8(float4 u, float4 v) {
    f16x8 h;
    h[0] = (_Float16)u.x; h[1] = (_Float16)u.y;
    h[2] = (_Float16)u.z; h[3] = (_Float16)u.w;
    h[4] = (_Float16)v.x; h[5] = (_Float16)v.y;
    h[6] = (_Float16)v.z; h[7] = (_Float16)v.w;
    return h;
}

// W scale: |W| <= 1/sqrt(512); map to [-127,127]
#define SW (127.0f * 22.627416997969522f)

__device__ __forceinline__ int quanw(float x) {
    return (int)rintf(fminf(fmaxf(x * SW, -127.0f), 127.0f));
}
__device__ __forceinline__ int packw4(float4 f) {
    int q0 = quanw(f.x), q1 = quanw(f.y), q2 = quanw(f.z), q3 = quanw(f.w);
    return (q0 & 255) | ((q1 & 255) << 8) | ((q2 & 255) << 16) | (q3 << 24);
}

// XOR bank swizzle for [*][64]-f16 LDS tiles: 16B-chunk index ^= row&7.
// Applied on BOTH ds_write (reg staging) and ds_read. off in f16 units (x8).
#define SWZ(row, off) ((row) * 64 + ((off) ^ (((row) & 7) << 3)))

// poll a monotone tile flag (relaxed), then one acquire fence.
// 4 polls per phase2 WG total -- NOT per-step (R4 lesson).
__device__ __forceinline__ void wait_tile(const unsigned int* c, unsigned int tgt) {
    while (__hip_atomic_load(c, __ATOMIC_RELAXED, __HIP_MEMORY_SCOPE_AGENT) < tgt) {
        __builtin_amdgcn_s_sleep(2);
    }
    __builtin_amdgcn_fence(__ATOMIC_ACQUIRE, "agent");
}

// ---------------- FUSED kernel.
// bids 0..63  : phase2 role, one batch each (dispatched first -> own CUs).
// bids 64..319: phase1 role, one 128x512 xp PANEL per (st,bb):
//               p = st*64 + bb. A-panel (128 emb rows) fetched ONCE (no
//               n-tile redundancy -> st=0 gather 64->16 MB); B (Wih) staged
//               per-kc into 64KB LDS, amortized over the full 512-col output
//               -> panel is matrix-bound (~9us).
// 84KB LDS/WG forces 1 WG/CU: round 1 = 64 p2 + 192 panels (st=0,1,2 all
// resident) -> batch b's tile-0 ready ~10-15us; p2 CUs never shared.
// Readiness: one WG per (st,bb) -> cnt[st*64+bb] = 1 (release); p2 WG b
// polls only its own column. One-way dependency -> deadlock-free.
__global__ __launch_bounds__(512, 1) void fused12(
    const int* __restrict__ idx, const float* __restrict__ emb,
    const float* __restrict__ Wih,
    const float* __restrict__ bih, const float* __restrict__ bhh,
    const float* __restrict__ Whh, float* __restrict__ out,
    unsigned int* __restrict__ cnt) {
    __shared__ __align__(16) unsigned char smem[84 * 1024];  // p1: Al+Bl; p2: himg

    const int tid  = threadIdx.x;
    const int bid  = blockIdx.x;
    const int wv   = tid >> 6;
    const int lane = tid & 63;
    const int n    = lane & 15;
    const int quad = lane >> 4;

    if (bid >= 64) {
        // ============ phase1 role: xp[128 x 512] = emb[idx] @ Wih^T + bias
        _Float16* Al = (_Float16*)smem;             // [128][64] swizzled
        _Float16* Bl = (_Float16*)(smem + 16384);   // [512][64] swizzled
        const int p  = bid - 64;        // 0..255
        const int st = p >> 6;          // s-tile 0..3
        const int bb = p & 63;          // batch
        const int m0 = bb * 512 + st * 128;

        // A staging: thread covers A-row tid>>2, chunks (tid&3)*2 + {0,1}.
        const int arow = tid >> 2;
        const int ac0  = (tid & 3) * 16;            // f16 col of chunk pair
        const int rowidx = idx[m0 + arow];
        const float* ap = emb + (size_t)rowidx * EE + ac0;
        const int aw0 = SWZ(arow, ac0);
        const int aw1 = SWZ(arow, ac0 + 8);
        // B staging: thread covers Wih row tid, all 8 chunks of the window.
        const float* bp = Wih + (size_t)tid * EE;

        const int mw  = wv & 1;         // row half (0..1)
        const int nwp = wv >> 1;        // col quarter (0..3), 128 cols each

        f32x4 acc[4][8];
#pragma unroll
        for (int mb = 0; mb < 4; ++mb)
#pragma unroll
            for (int nb = 0; nb < 8; ++nb) acc[mb][nb] = (f32x4){0.f, 0.f, 0.f, 0.f};

        for (int kc = 0; kc < 8; ++kc) {
            {
                const float4* la = (const float4*)(ap + kc * 64);
                float4 a0 = la[0], a1 = la[1], a2 = la[2], a3 = la[3];
                *(f16x8*)&Al[aw0] = pack8(a0, a1);
                *(f16x8*)&Al[aw1] = pack8(a2, a3);
            }
#pragma unroll
            for (int ch = 0; ch < 8; ++ch) {
                const float4* lb = (const float4*)(bp + kc * 64 + ch * 8);
                *(f16x8*)&Bl[SWZ(tid, ch * 8)] = pack8(lb[0], lb[1]);
            }
            __syncthreads();

#pragma unroll
            for (int kk = 0; kk < 2; ++kk) {
                // group 0: nb 0..3
                f16x8 bfr[4];
#pragma unroll
                for (int nb = 0; nb < 4; ++nb)
                    bfr[nb] = *(const f16x8*)&Bl[SWZ(nwp * 128 + nb * 16 + n, kk * 32 + quad * 8)];
#pragma unroll
                for (int mb = 0; mb < 4; ++mb) {
                    f16x8 afr = *(const f16x8*)&Al[SWZ(mw * 64 + mb * 16 + n, kk * 32 + quad * 8)];
#pragma unroll
                    for (int nb = 0; nb < 4; ++nb)
                        acc[mb][nb] = __builtin_amdgcn_mfma_f32_16x16x32_f16(
                            afr, bfr[nb], acc[mb][nb], 0, 0, 0);
                }
                // group 1: nb 4..7
#pragma unroll
                for (int nb = 0; nb < 4; ++nb)
                    bfr[nb] = *(const f16x8*)&Bl[SWZ(nwp * 128 + (nb + 4) * 16 + n, kk * 32 + quad * 8)];
#pragma unroll
                for (int mb = 0; mb < 4; ++mb) {
                    f16x8 afr = *(const f16x8*)&Al[SWZ(mw * 64 + mb * 16 + n, kk * 32 + quad * 8)];
#pragma unroll
                    for (int nb = 0; nb < 4; ++nb)
                        acc[mb][nb + 4] = __builtin_amdgcn_mfma_f32_16x16x32_f16(
                            afr, bfr[nb], acc[mb][nb + 4], 0, 0, 0);
                }
            }
            __syncthreads();
        }

        int   cc[8];
        float bv[8];
#pragma unroll
        for (int nb = 0; nb < 8; ++nb) {
            cc[nb] = nwp * 128 + nb * 16 + n;
            bv[nb] = bih[cc[nb]] + bhh[cc[nb]];
        }
#pragma unroll
        for (int mb = 0; mb < 4; ++mb) {
            int rowg = m0 + mw * 64 + mb * 16 + quad * 4;
#pragma unroll
            for (int nb = 0; nb < 8; ++nb) {
#pragma unroll
                for (int i = 0; i < 4; ++i)
                    out[(size_t)(rowg + i) * HH + cc[nb]] = acc[mb][nb][i] + bv[nb];
            }
        }
        // completion: drain own stores, barrier, one release + flag.
        __asm__ volatile("s_waitcnt vmcnt(0)" ::: "memory");
        __syncthreads();
        if (tid == 0) {
            __builtin_amdgcn_fence(__ATOMIC_RELEASE, "agent");
            __hip_atomic_store(cnt + st * 64 + bb, 1u, __ATOMIC_RELAXED,
                               __HIP_MEMORY_SCOPE_AGENT);
        }
        return;
    }

    // ================= phase2 role (v3b recurrence, batch = bid) =========
    unsigned char* h0p = smem;          // ping-pong i8 h images (512 B each)
    unsigned char* h1p = smem + 512;
    const int b = bid;

    iv4 areg[4][8];
#pragma unroll
    for (int mb = 0; mb < 4; ++mb) {
        const float* wr = Whh + (size_t)(wv * 64 + mb * 16 + n) * HH + quad * 16;
#pragma unroll
        for (int j = 0; j < 8; ++j) {
            int kb = (j < 7) ? ((wv + 1 + j) & 7) : wv;
            const float4* ptr = (const float4*)(wr + kb * 64);
            iv4 v;
            v[0] = packw4(ptr[0]);
            v[1] = packw4(ptr[1]);
            v[2] = packw4(ptr[2]);
            v[3] = packw4(ptr[3]);
            areg[mb][j] = v;
        }
    }
    if (tid < 64) ((u64*)h0p)[tid] = 0ull;   // h0 = 0
    __syncthreads();

    const int  ilo = n & 1;
    const int  ihi = (n >> 1) & 1;
    const bool sb0 = ((n >> 2) & 1) != 0;
    const bool sb1 = ((n >> 3) & 1) != 0;
    const int  row = wv * 64 + ((n >> 2) & 3) * 16 + quad * 4 + (n & 3);
    float* obase = out + (size_t)b * (SS * HH) + row;

    int koff[7];
#pragma unroll
    for (int j = 0; j < 7; ++j) koff[j] = ((wv + 1 + j) & 7) * 64 + quad * 16;
    const int oown = wv * 64 + quad * 16;

    const float inv2 = (2.0f * 1.4426950408889634f) / (SW * 127.0f);
    const float K2   = 2.0f * 1.4426950408889634f;

    iv4 acc0 = (iv4){0,0,0,0}, acc1 = (iv4){0,0,0,0};
    iv4 acc2 = (iv4){0,0,0,0}, acc3 = (iv4){0,0,0,0};

    wait_tile(cnt + b, 1u);             // xp panel (st=0, this batch) ready
    float xp2_c = obase[0] * K2;
    float xp2_n = obase[HH] * K2;
    float hl = 0.f;

#define RNN_STEP(T, HBR, HNX)                                                  \
    {                                                                          \
        if ((((T) + 2) & 127) == 0 && ((T) + 2) < SS)                          \
            wait_tile(cnt + ((((T) + 2) >> 7) * 64 + b), 1u);                  \
        float xp_f = obase[(size_t)((T) + 2) * HH];                            \
        _Pragma("unroll")                                                      \
        for (int j = 0; j < 7; ++j) {                                          \
            iv4 bfr = *(const iv4*)((HBR) + koff[j]);                          \
            acc0 = __builtin_amdgcn_mfma_i32_16x16x64_i8(areg[0][j], bfr, acc0, 0, 0, 0); \
            acc1 = __builtin_amdgcn_mfma_i32_16x16x64_i8(areg[1][j], bfr, acc1, 0, 0, 0); \
            acc2 = __builtin_amdgcn_mfma_i32_16x16x64_i8(areg[2][j], bfr, acc2, 0, 0, 0); \
            acc3 = __builtin_amdgcn_mfma_i32_16x16x64_i8(areg[3][j], bfr, acc3, 0, 0, 0); \
        }                                                                      \
        iv4 sa = sb0 ? acc1 : acc0;                                            \
        iv4 sc = sb0 ? acc3 : acc2;                                            \
        iv4 s  = sb1 ? sc : sa;                                                \
        int zA = ilo ? s[1] : s[0];                                            \
        int zB = ilo ? s[3] : s[2];                                            \
        int z  = ihi ? zB : zA;                                                \
        float u  = fmaf((float)z, inv2, xp2_c);                                \
        float ex;                                                              \
        __asm__("v_exp_f32 %0, %1" : "=v"(ex) : "v"(u));                       \
        float rr = __builtin_amdgcn_rcpf(ex + 1.0f);                           \
        int   q  = (int)rintf(fmaf(rr, -254.0f, 127.0f));                      \
        *(char*)((HNX) + row) = (char)q;                                       \
        iv4 bown = *(const iv4*)((HNX) + oown);                                \
        acc0 = __builtin_amdgcn_mfma_i32_16x16x64_i8(areg[0][7], bown, (iv4){0,0,0,0}, 0, 0, 0); \
        acc1 = __builtin_amdgcn_mfma_i32_16x16x64_i8(areg[1][7], bown, (iv4){0,0,0,0}, 0, 0, 0); \
        acc2 = __builtin_amdgcn_mfma_i32_16x16x64_i8(areg[2][7], bown, (iv4){0,0,0,0}, 0, 0, 0); \
        acc3 = __builtin_amdgcn_mfma_i32_16x16x64_i8(areg[3][7], bown, (iv4){0,0,0,0}, 0, 0, 0); \
        float h = fmaf(rr, -2.0f, 1.0f);                                       \
        obase[(size_t)(T) * HH] = h;                                           \
        hl = h;                                                                \
        __builtin_amdgcn_sched_barrier(0);                                     \
        __asm__ volatile("s_waitcnt lgkmcnt(0)\n\ts_barrier" ::: "memory");    \
        xp2_c = xp2_n; xp2_n = xp_f * K2;                                      \
    }

    for (int t = 0; t < SS; t += 2) {
        RNN_STEP(t,     h0p, h1p);
        RNN_STEP(t + 1, h1p, h0p);
    }
#undef RNN_STEP

    out[BSH + (size_t)b * HH + row] = hl;
}

// ---------------- Fallbacks (no workspace): serial f32 phase1 + solo phase2.
__global__ __launch_bounds__(256, 3) void phase1(
    const int* __restrict__ idx, const float* __restrict__ emb,
    const float* __restrict__ Wih, const float* __restrict__ bih,
    const float* __restrict__ bhh, float* __restrict__ out) {
    __shared__ __align__(16) _Float16 Al[128 * 72];
    __shared__ __align__(16) _Float16 Bl[128 * 72];

    const int tid  = threadIdx.x;
    const int m0   = (blockIdx.x >> 2) * 128;
    const int n0   = (blockIdx.x & 3) * 128;
    const int wv   = tid >> 6;
    const int lane = tid & 63;
    const int n    = lane & 15;
    const int quad = lane >> 4;
    const int mw   = wv >> 1;
    const int nw   = wv & 1;

    const int sr = tid >> 1;
    const int kh = (tid & 1) * 32;
    const int rowidx = idx[m0 + sr];
    const float* ap = emb + (size_t)rowidx * EE + kh;
    const float* bp = Wih + (size_t)(n0 + sr) * EE + kh;

    f32x4 acc[4][4];
#pragma unroll
    for (int a = 0; a < 4; ++a)
#pragma unroll
        for (int c = 0; c < 4; ++c) acc[a][c] = (f32x4){0.f, 0.f, 0.f, 0.f};

    for (int kc = 0; kc < 8; ++kc) {
#pragma unroll
        for (int q = 0; q < 4; ++q) {
            float4 u = *(const float4*)(ap + kc * 64 + q * 8);
            float4 v = *(const float4*)(ap + kc * 64 + q * 8 + 4);
            *(f16x8*)&Al[sr * 72 + kh + q * 8] = pack8(u, v);
        }
#pragma unroll
        for (int q = 0; q < 4; ++q) {
            float4 u = *(const float4*)(bp + kc * 64 + q * 8);
            float4 v = *(const float4*)(bp + kc * 64 + q * 8 + 4);
            *(f16x8*)&Bl[sr * 72 + kh + q * 8] = pack8(u, v);
        }
        __syncthreads();

#pragma unroll
        for (int kk = 0; kk < 2; ++kk) {
            f16x8 bfr[4];
#pragma unroll
            for (int nb = 0; nb < 4; ++nb)
                bfr[nb] = *(const f16x8*)&Bl[(nw * 64 + nb * 16 + n) * 72 + kk * 32 + quad * 8];
#pragma unroll
            for (int mb = 0; mb < 4; ++mb) {
                f16x8 afr = *(const f16x8*)&Al[(mw * 64 + mb * 16 + n) * 72 + kk * 32 + quad * 8];
#pragma unroll
                for (int nb = 0; nb < 4; ++nb)
                    acc[mb][nb] = __builtin_amdgcn_mfma_f32_16x16x32_f16(
                        afr, bfr[nb], acc[mb][nb], 0, 0, 0);
            }
        }
        __syncthreads();
    }

    int   cc[4];
    float bv[4];
#pragma unroll
    for (int nb = 0; nb < 4; ++nb) {
        cc[nb] = n0 + nw * 64 + nb * 16 + n;
        bv[nb] = bih[cc[nb]] + bhh[cc[nb]];
    }
#pragma unroll
    for (int mb = 0; mb < 4; ++mb) {
        int rowg = m0 + mw * 64 + mb * 16 + quad * 4;
#pragma unroll
        for (int nb = 0; nb < 4; ++nb) {
#pragma unroll
            for (int i = 0; i < 4; ++i)
                out[(size_t)(rowg + i) * HH + cc[nb]] = acc[mb][nb][i] + bv[nb];
        }
    }
}

__global__ __launch_bounds__(512, 1) void phase2(
    const float* __restrict__ Whh, float* __restrict__ out) {
    __shared__ __align__(16) unsigned char himg[2][512];

    const int tid  = threadIdx.x;
    const int b    = blockIdx.x;
    const int wv   = tid >> 6;
    const int lane = tid & 63;
    const int n    = lane & 15;
    const int quad = lane >> 4;

    iv4 areg[4][8];
#pragma unroll
    for (int mb = 0; mb < 4; ++mb) {
        const float* wr = Whh + (size_t)(wv * 64 + mb * 16 + n) * HH + quad * 16;
#pragma unroll
        for (int j = 0; j < 8; ++j) {
            int kb = (j < 7) ? ((wv + 1 + j) & 7) : wv;
            const float4* p = (const float4*)(wr + kb * 64);
            iv4 v;
            v[0] = packw4(p[0]);
            v[1] = packw4(p[1]);
            v[2] = packw4(p[2]);
            v[3] = packw4(p[3]);
            areg[mb][j] = v;
        }
    }
    if (tid < 64) ((u64*)himg[0])[tid] = 0ull;
    __syncthreads();

    const int  ilo = n & 1;
    const int  ihi = (n >> 1) & 1;
    const bool sb0 = ((n >> 2) & 1) != 0;
    const bool sb1 = ((n >> 3) & 1) != 0;
    const int  row = wv * 64 + ((n >> 2) & 3) * 16 + quad * 4 + (n & 3);
    float* obase = out + (size_t)b * (SS * HH) + row;

    int koff[7];
#pragma unroll
    for (int j = 0; j < 7; ++j) koff[j] = ((wv + 1 + j) & 7) * 64 + quad * 16;
    const int oown = wv * 64 + quad * 16;

    const float inv2 = (2.0f * 1.4426950408889634f) / (SW * 127.0f);
    const float K2   = 2.0f * 1.4426950408889634f;

    iv4 acc0 = (iv4){0,0,0,0}, acc1 = (iv4){0,0,0,0};
    iv4 acc2 = (iv4){0,0,0,0}, acc3 = (iv4){0,0,0,0};

    float xp2_c = obase[0] * K2;
    float xp2_n = obase[HH] * K2;
    float hl = 0.f;
    unsigned char* h0p = himg[0];
    unsigned char* h1p = himg[1];

#define RNN_STEP(T, HBR, HNX)                                                  \
    {                                                                          \
        float xp_f = obase[(size_t)((T) + 2) * HH];                            \
        _Pragma("unroll")                                                      \
        for (int j = 0; j < 7; ++j) {                                          \
            iv4 bfr = *(const iv4*)((HBR) + koff[j]);                          \
            acc0 = __builtin_amdgcn_mfma_i32_16x16x64_i8(areg[0][j], bfr, acc0, 0, 0, 0); \
            acc1 = __builtin_amdgcn_mfma_i32_16x16x64_i8(areg[1][j], bfr, acc1, 0, 0, 0); \
            acc2 = __builtin_amdgcn_mfma_i32_16x16x64_i8(areg[2][j], bfr, acc2, 0, 0, 0); \
            acc3 = __builtin_amdgcn_mfma_i32_16x16x64_i8(areg[3][j], bfr, acc3, 0, 0, 0); \
        }                                                                      \
        iv4 sa = sb0 ? acc1 : acc0;                                            \
        iv4 sc = sb0 ? acc3 : acc2;                                            \
        iv4 s  = sb1 ? sc : sa;                                                \
        int zA = ilo ? s[1] : s[0];                                            \
        int zB = ilo ? s[3] : s[2];                                            \
        int z  = ihi ? zB : zA;                                                \
        float u  = fmaf((float)z, inv2, xp2_c);                                \
        float ex;                                                              \
        __asm__("v_exp_f32 %0, %1" : "=v"(ex) : "v"(u));                       \
        float rr = __builtin_amdgcn_rcpf(ex + 1.0f);                           \
        int   q  = (int)rintf(fmaf(rr, -254.0f, 127.0f));                      \
        *(char*)((HNX) + row) = (char)q;                                       \
        iv4 bown = *(const iv4*)((HNX) + oown);                                \
        acc0 = __builtin_amdgcn_mfma_i32_16x16x64_i8(areg[0][7], bown, (iv4){0,0,0,0}, 0, 0, 0); \
        acc1 = __builtin_amdgcn_mfma_i32_16x16x64_i8(areg[1][7], bown, (iv4){0,0,0,0}, 0, 0, 0); \
        acc2 = __builtin_amdgcn_mfma_i32_16x16x64_i8(areg[2][7], bown, (iv4){0,0,0,0}, 0, 0, 0); \
        acc3 = __builtin_amdgcn_mfma_i32_16x16x64_i8(areg[3][7], bown, (iv4){0,0,0,0}, 0, 0, 0); \
        float h = fmaf(rr, -2.0f, 1.0f);                                       \
        obase[(size_t)(T) * HH] = h;                                           \
        hl = h;                                                                \
        __builtin_amdgcn_sched_barrier(0);                                     \
        __asm__ volatile("s_waitcnt lgkmcnt(0)\n\ts_barrier" ::: "memory");    \
        xp2_c = xp2_n; xp2_n = xp_f * K2;                                      \
    }

    for (int t = 0; t < SS; t += 2) {
        RNN_STEP(t,     h0p, h1p);
        RNN_STEP(t + 1, h1p, h0p);
    }
#undef RNN_STEP

    out[BSH + (size_t)b * HH + row] = hl;
}

extern "C" void kernel_launch(void* const* d_in, const int* in_sizes, int n_in,
                              void* d_out, int out_size, void* d_ws, size_t ws_size,
                              hipStream_t stream) {
    const int*   idx = (const int*)d_in[0];
    const float* emb = (const float*)d_in[1];
    const float* Wih = (const float*)d_in[2];
    const float* Whh = (const float*)d_in[3];
    const float* bih = (const float*)d_in[4];
    const float* bhh = (const float*)d_in[5];
    float* out = (float*)d_out;

    const size_t CNTBYTES = 256 * sizeof(unsigned int);  // (st,batch) flags

    if (d_ws && ws_size >= CNTBYTES) {
        unsigned int* cnt = (unsigned int*)d_ws;
        hipMemsetAsync(cnt, 0, CNTBYTES, stream);
        fused12<<<dim3(64 + 256), dim3(512), 0, stream>>>(
            idx, emb, Wih, bih, bhh, Whh, out, cnt);
    } else {
        phase1<<<dim3(1024), dim3(256), 0, stream>>>(idx, emb, Wih, bih, bhh, out);
        phase2<<<dim3(64), dim3(512), 0, stream>>>(Whh, out);
    }
}

// Round 9
// 487.394 us; speedup vs baseline: 1.1346x; 1.0995x over previous
//
#include <hip/hip_runtime.h>
#include <cstdint>

#define BB 64
#define SS 512
#define HH 512
#define EE 512
#define BSH (BB*SS*HH)

typedef _Float16 f16x8 __attribute__((ext_vector_type(8)));
typedef float    f32x4 __attribute__((ext_vector_type(4)));
typedef int      iv4   __attribute__((ext_vector_type(4)));
typedef unsigned long long u64;

__device__ __forceinline__ f16x8 pack8(float4 u, float4 v) {
    f16x8 h;
    h[0] = (_Float16)u.x; h[1] = (_Float16)u.y;
    h[2] = (_Float16)u.z; h[3] = (_Float16)u.w;
    h[4] = (_Float16)v.x; h[5] = (_Float16)v.y;
    h[6] = (_Float16)v.z; h[7] = (_Float16)v.w;
    return h;
}

// W scale: |W| <= 1/sqrt(512); map to [-127,127]
#define SW (127.0f * 22.627416997969522f)

__device__ __forceinline__ int quanw(float x) {
    return (int)rintf(fminf(fmaxf(x * SW, -127.0f), 127.0f));
}
__device__ __forceinline__ int packw4(float4 f) {
    int q0 = quanw(f.x), q1 = quanw(f.y), q2 = quanw(f.z), q3 = quanw(f.w);
    return (q0 & 255) | ((q1 & 255) << 8) | ((q2 & 255) << 16) | (q3 << 24);
}

// XOR bank swizzle for [*][64]-f16 LDS tiles: 16B-chunk index ^= row&7.
#define SWZ(row, off) ((row) * 64 + ((off) ^ (((row) & 7) << 3)))

// poll a monotone flag (relaxed), then ONE acquire fence (R4 lesson:
// never per-step). p2 executes 5 of these total (1 quant + 4 s-tiles).
__device__ __forceinline__ void wait_tile(const unsigned int* c, unsigned int tgt) {
    while (__hip_atomic_load(c, __ATOMIC_RELAXED, __HIP_MEMORY_SCOPE_AGENT) < tgt) {
        __builtin_amdgcn_s_sleep(2);
    }
    __builtin_amdgcn_fence(__ATOMIC_ACQUIRE, "agent");
}

// ---------------- FUSED kernel, 4 roles by bid (dispatch-order = priority):
//   0..15   : quant Whh f32 -> i8 (256 KB ws image), flag cnt[256] += 1 (x16)
//   16..79  : phase2, batch b = bid-16; waits quant flag, then areg = 256KB i8
//   80..207 : st=0 HALF-panels 128x256 (p=bid-80: bb=p>>1, nh=p&1) -> earlier
//             readiness (cnt[bb] += 1, target 2)
//   208..399: st=1..3 full panels 128x512 (q=bid-208: st=1+(q>>6), bb=q&63),
//             cnt[st*64+bb] = 1
// Only p2 ever waits; quant/panels are wait-free -> guaranteed progress.
__global__ __launch_bounds__(512, 1) void fused12(
    const int* __restrict__ idx, const float* __restrict__ emb,
    const float* __restrict__ Wih,
    const float* __restrict__ bih, const float* __restrict__ bhh,
    const float* __restrict__ Whh, float* __restrict__ out,
    unsigned int* __restrict__ cnt, unsigned char* __restrict__ whh8) {
    __shared__ __align__(16) unsigned char smem[84 * 1024];

    const int tid  = threadIdx.x;
    const int bid  = blockIdx.x;
    const int wv   = tid >> 6;
    const int lane = tid & 63;
    const int n    = lane & 15;
    const int quad = lane >> 4;

    if (bid < 16) {
        // ============ quant role: whh8 = packw4(Whh), row-major i8 =========
        const int base = (bid * 512 + tid) * 32;   // f32 element index
        const float* src = Whh + base;
        int d[8];
#pragma unroll
        for (int c = 0; c < 8; ++c) {
            const float4* pp = (const float4*)(src + c * 4);
            d[c] = packw4(pp[0]);
        }
        *(iv4*)(whh8 + base)      = (iv4){d[0], d[1], d[2], d[3]};
        *(iv4*)(whh8 + base + 16) = (iv4){d[4], d[5], d[6], d[7]};
        __asm__ volatile("s_waitcnt vmcnt(0)" ::: "memory");
        __syncthreads();
        if (tid == 0) {
            __builtin_amdgcn_fence(__ATOMIC_RELEASE, "agent");
            __hip_atomic_fetch_add(cnt + 256, 1u, __ATOMIC_RELAXED,
                                   __HIP_MEMORY_SCOPE_AGENT);
        }
        return;
    }

    if (bid >= 80 && bid < 208) {
        // ============ st=0 HALF-panel: xp[128 x 256], batch bb, half nh ====
        _Float16* Al = (_Float16*)smem;             // [128][64] swizzled
        _Float16* Bl = (_Float16*)(smem + 16384);   // [256][64] swizzled
        const int p  = bid - 80;
        const int bb = p >> 1;
        const int nh = p & 1;
        const int m0 = bb * 512;                    // st = 0
        const int nbase = nh * 256;

        const int arow = tid >> 2;
        const int ac0  = (tid & 3) * 16;
        const int rowidx = idx[m0 + arow];
        const float* ap = emb + (size_t)rowidx * EE + ac0;
        const int aw0 = SWZ(arow, ac0);
        const int aw1 = SWZ(arow, ac0 + 8);
        const int brow = tid >> 1;
        const int bc0  = (tid & 1) * 32;
        const float* bp = Wih + (size_t)(nbase + brow) * EE + bc0;

        const int mw  = wv & 1;         // row half
        const int nwq = wv >> 1;        // 64-col quarter of the 256

        f32x4 acc[4][4];
#pragma unroll
        for (int mb = 0; mb < 4; ++mb)
#pragma unroll
            for (int nb = 0; nb < 4; ++nb) acc[mb][nb] = (f32x4){0.f, 0.f, 0.f, 0.f};

        for (int kc = 0; kc < 8; ++kc) {
            {
                const float4* la = (const float4*)(ap + kc * 64);
                *(f16x8*)&Al[aw0] = pack8(la[0], la[1]);
                *(f16x8*)&Al[aw1] = pack8(la[2], la[3]);
            }
#pragma unroll
            for (int ch = 0; ch < 4; ++ch) {
                const float4* lb = (const float4*)(bp + kc * 64 + ch * 8);
                *(f16x8*)&Bl[SWZ(brow, bc0 + ch * 8)] = pack8(lb[0], lb[1]);
            }
            __syncthreads();

#pragma unroll
            for (int kk = 0; kk < 2; ++kk) {
                f16x8 bfr[4];
#pragma unroll
                for (int nb = 0; nb < 4; ++nb)
                    bfr[nb] = *(const f16x8*)&Bl[SWZ(nwq * 64 + nb * 16 + n, kk * 32 + quad * 8)];
#pragma unroll
                for (int mb = 0; mb < 4; ++mb) {
                    f16x8 afr = *(const f16x8*)&Al[SWZ(mw * 64 + mb * 16 + n, kk * 32 + quad * 8)];
#pragma unroll
                    for (int nb = 0; nb < 4; ++nb)
                        acc[mb][nb] = __builtin_amdgcn_mfma_f32_16x16x32_f16(
                            afr, bfr[nb], acc[mb][nb], 0, 0, 0);
                }
            }
            __syncthreads();
        }

        int   cc[4];
        float bv[4];
#pragma unroll
        for (int nb = 0; nb < 4; ++nb) {
            cc[nb] = nbase + nwq * 64 + nb * 16 + n;
            bv[nb] = bih[cc[nb]] + bhh[cc[nb]];
        }
#pragma unroll
        for (int mb = 0; mb < 4; ++mb) {
            int rowg = m0 + mw * 64 + mb * 16 + quad * 4;
#pragma unroll
            for (int nb = 0; nb < 4; ++nb) {
#pragma unroll
                for (int i = 0; i < 4; ++i)
                    out[(size_t)(rowg + i) * HH + cc[nb]] = acc[mb][nb][i] + bv[nb];
            }
        }
        __asm__ volatile("s_waitcnt vmcnt(0)" ::: "memory");
        __syncthreads();
        if (tid == 0) {
            __builtin_amdgcn_fence(__ATOMIC_RELEASE, "agent");
            __hip_atomic_fetch_add(cnt + bb, 1u, __ATOMIC_RELAXED,
                                   __HIP_MEMORY_SCOPE_AGENT);
        }
        return;
    }

    if (bid >= 208) {
        // ============ st=1..3 full panel: xp[128 x 512] ====================
        _Float16* Al = (_Float16*)smem;             // [128][64] swizzled
        _Float16* Bl = (_Float16*)(smem + 16384);   // [512][64] swizzled
        const int q  = bid - 208;       // 0..191
        const int st = 1 + (q >> 6);
        const int bb = q & 63;
        const int m0 = bb * 512 + st * 128;

        const int arow = tid >> 2;
        const int ac0  = (tid & 3) * 16;
        const int rowidx = idx[m0 + arow];
        const float* ap = emb + (size_t)rowidx * EE + ac0;
        const int aw0 = SWZ(arow, ac0);
        const int aw1 = SWZ(arow, ac0 + 8);
        const float* bp = Wih + (size_t)tid * EE;

        const int mw  = wv & 1;
        const int nwp = wv >> 1;

        f32x4 acc[4][8];
#pragma unroll
        for (int mb = 0; mb < 4; ++mb)
#pragma unroll
            for (int nb = 0; nb < 8; ++nb) acc[mb][nb] = (f32x4){0.f, 0.f, 0.f, 0.f};

        for (int kc = 0; kc < 8; ++kc) {
            {
                const float4* la = (const float4*)(ap + kc * 64);
                *(f16x8*)&Al[aw0] = pack8(la[0], la[1]);
                *(f16x8*)&Al[aw1] = pack8(la[2], la[3]);
            }
#pragma unroll
            for (int ch = 0; ch < 8; ++ch) {
                const float4* lb = (const float4*)(bp + kc * 64 + ch * 8);
                *(f16x8*)&Bl[SWZ(tid, ch * 8)] = pack8(lb[0], lb[1]);
            }
            __syncthreads();

#pragma unroll
            for (int kk = 0; kk < 2; ++kk) {
                f16x8 bfr[4];
#pragma unroll
                for (int nb = 0; nb < 4; ++nb)
                    bfr[nb] = *(const f16x8*)&Bl[SWZ(nwp * 128 + nb * 16 + n, kk * 32 + quad * 8)];
#pragma unroll
                for (int mb = 0; mb < 4; ++mb) {
                    f16x8 afr = *(const f16x8*)&Al[SWZ(mw * 64 + mb * 16 + n, kk * 32 + quad * 8)];
#pragma unroll
                    for (int nb = 0; nb < 4; ++nb)
                        acc[mb][nb] = __builtin_amdgcn_mfma_f32_16x16x32_f16(
                            afr, bfr[nb], acc[mb][nb], 0, 0, 0);
                }
#pragma unroll
                for (int nb = 0; nb < 4; ++nb)
                    bfr[nb] = *(const f16x8*)&Bl[SWZ(nwp * 128 + (nb + 4) * 16 + n, kk * 32 + quad * 8)];
#pragma unroll
                for (int mb = 0; mb < 4; ++mb) {
                    f16x8 afr = *(const f16x8*)&Al[SWZ(mw * 64 + mb * 16 + n, kk * 32 + quad * 8)];
#pragma unroll
                    for (int nb = 0; nb < 4; ++nb)
                        acc[mb][nb + 4] = __builtin_amdgcn_mfma_f32_16x16x32_f16(
                            afr, bfr[nb], acc[mb][nb + 4], 0, 0, 0);
                }
            }
            __syncthreads();
        }

        int   cc[8];
        float bv[8];
#pragma unroll
        for (int nb = 0; nb < 8; ++nb) {
            cc[nb] = nwp * 128 + nb * 16 + n;
            bv[nb] = bih[cc[nb]] + bhh[cc[nb]];
        }
#pragma unroll
        for (int mb = 0; mb < 4; ++mb) {
            int rowg = m0 + mw * 64 + mb * 16 + quad * 4;
#pragma unroll
            for (int nb = 0; nb < 8; ++nb) {
#pragma unroll
                for (int i = 0; i < 4; ++i)
                    out[(size_t)(rowg + i) * HH + cc[nb]] = acc[mb][nb][i] + bv[nb];
            }
        }
        __asm__ volatile("s_waitcnt vmcnt(0)" ::: "memory");
        __syncthreads();
        if (tid == 0) {
            __builtin_amdgcn_fence(__ATOMIC_RELEASE, "agent");
            __hip_atomic_store(cnt + st * 64 + bb, 1u, __ATOMIC_RELAXED,
                               __HIP_MEMORY_SCOPE_AGENT);
        }
        return;
    }

    // ================= phase2 role (v3b recurrence, batch = bid-16) =======
    unsigned char* h0p = smem;
    unsigned char* h1p = smem + 512;
    const int b = bid - 16;

    wait_tile(cnt + 256, 16u);          // whh8 ready (one poll, one fence)

    iv4 areg[4][8];
#pragma unroll
    for (int mb = 0; mb < 4; ++mb) {
        const unsigned char* wr = whh8 + (size_t)(wv * 64 + mb * 16 + n) * HH + quad * 16;
#pragma unroll
        for (int j = 0; j < 8; ++j) {
            int kb = (j < 7) ? ((wv + 1 + j) & 7) : wv;
            areg[mb][j] = *(const iv4*)(wr + kb * 64);
        }
    }
    if (tid < 64) ((u64*)h0p)[tid] = 0ull;   // h0 = 0
    __syncthreads();

    const int  ilo = n & 1;
    const int  ihi = (n >> 1) & 1;
    const bool sb0 = ((n >> 2) & 1) != 0;
    const bool sb1 = ((n >> 3) & 1) != 0;
    const int  row = wv * 64 + ((n >> 2) & 3) * 16 + quad * 4 + (n & 3);
    float* obase = out + (size_t)b * (SS * HH) + row;

    int koff[7];
#pragma unroll
    for (int j = 0; j < 7; ++j) koff[j] = ((wv + 1 + j) & 7) * 64 + quad * 16;
    const int oown = wv * 64 + quad * 16;

    const float inv2 = (2.0f * 1.4426950408889634f) / (SW * 127.0f);
    const float K2   = 2.0f * 1.4426950408889634f;

    iv4 acc0 = (iv4){0,0,0,0}, acc1 = (iv4){0,0,0,0};
    iv4 acc2 = (iv4){0,0,0,0}, acc3 = (iv4){0,0,0,0};

    wait_tile(cnt + b, 2u);             // st=0 xp (both halves) ready
    float xp2_c = obase[0] * K2;
    float xp2_n = obase[HH] * K2;
    float hl = 0.f;

#define RNN_STEP(T, HBR, HNX)                                                  \
    {                                                                          \
        if ((((T) + 2) & 127) == 0 && ((T) + 2) < SS)                          \
            wait_tile(cnt + ((((T) + 2) >> 7) * 64 + b), 1u);                  \
        float xp_f = obase[(size_t)((T) + 2) * HH];                            \
        _Pragma("unroll")                                                      \
        for (int j = 0; j < 7; ++j) {                                          \
            iv4 bfr = *(const iv4*)((HBR) + koff[j]);                          \
            acc0 = __builtin_amdgcn_mfma_i32_16x16x64_i8(areg[0][j], bfr, acc0, 0, 0, 0); \
            acc1 = __builtin_amdgcn_mfma_i32_16x16x64_i8(areg[1][j], bfr, acc1, 0, 0, 0); \
            acc2 = __builtin_amdgcn_mfma_i32_16x16x64_i8(areg[2][j], bfr, acc2, 0, 0, 0); \
            acc3 = __builtin_amdgcn_mfma_i32_16x16x64_i8(areg[3][j], bfr, acc3, 0, 0, 0); \
        }                                                                      \
        iv4 sa = sb0 ? acc1 : acc0;                                            \
        iv4 sc = sb0 ? acc3 : acc2;                                            \
        iv4 s  = sb1 ? sc : sa;                                                \
        int zA = ilo ? s[1] : s[0];                                            \
        int zB = ilo ? s[3] : s[2];                                            \
        int z  = ihi ? zB : zA;                                                \
        float u  = fmaf((float)z, inv2, xp2_c);                                \
        float ex;                                                              \
        __asm__("v_exp_f32 %0, %1" : "=v"(ex) : "v"(u));                       \
        float rr = __builtin_amdgcn_rcpf(ex + 1.0f);                           \
        int   qv = (int)rintf(fmaf(rr, -254.0f, 127.0f));                      \
        *(char*)((HNX) + row) = (char)qv;                                      \
        iv4 bown = *(const iv4*)((HNX) + oown);                                \
        acc0 = __builtin_amdgcn_mfma_i32_16x16x64_i8(areg[0][7], bown, (iv4){0,0,0,0}, 0, 0, 0); \
        acc1 = __builtin_amdgcn_mfma_i32_16x16x64_i8(areg[1][7], bown, (iv4){0,0,0,0}, 0, 0, 0); \
        acc2 = __builtin_amdgcn_mfma_i32_16x16x64_i8(areg[2][7], bown, (iv4){0,0,0,0}, 0, 0, 0); \
        acc3 = __builtin_amdgcn_mfma_i32_16x16x64_i8(areg[3][7], bown, (iv4){0,0,0,0}, 0, 0, 0); \
        float h = fmaf(rr, -2.0f, 1.0f);                                       \
        obase[(size_t)(T) * HH] = h;                                           \
        hl = h;                                                                \
        __builtin_amdgcn_sched_barrier(0);                                     \
        __asm__ volatile("s_waitcnt lgkmcnt(0)\n\ts_barrier" ::: "memory");    \
        xp2_c = xp2_n; xp2_n = xp_f * K2;                                      \
    }

    for (int t = 0; t < SS; t += 2) {
        RNN_STEP(t,     h0p, h1p);
        RNN_STEP(t + 1, h1p, h0p);
    }
#undef RNN_STEP

    out[BSH + (size_t)b * HH + row] = hl;
}

// ---------------- Fallbacks (no workspace): serial f32 phase1 + solo phase2.
__global__ __launch_bounds__(256, 3) void phase1(
    const int* __restrict__ idx, const float* __restrict__ emb,
    const float* __restrict__ Wih, const float* __restrict__ bih,
    const float* __restrict__ bhh, float* __restrict__ out) {
    __shared__ __align__(16) _Float16 Al[128 * 72];
    __shared__ __align__(16) _Float16 Bl[128 * 72];

    const int tid  = threadIdx.x;
    const int m0   = (blockIdx.x >> 2) * 128;
    const int n0   = (blockIdx.x & 3) * 128;
    const int wv   = tid >> 6;
    const int lane = tid & 63;
    const int n    = lane & 15;
    const int quad = lane >> 4;
    const int mw   = wv >> 1;
    const int nw   = wv & 1;

    const int sr = tid >> 1;
    const int kh = (tid & 1) * 32;
    const int rowidx = idx[m0 + sr];
    const float* ap = emb + (size_t)rowidx * EE + kh;
    const float* bp = Wih + (size_t)(n0 + sr) * EE + kh;

    f32x4 acc[4][4];
#pragma unroll
    for (int a = 0; a < 4; ++a)
#pragma unroll
        for (int c = 0; c < 4; ++c) acc[a][c] = (f32x4){0.f, 0.f, 0.f, 0.f};

    for (int kc = 0; kc < 8; ++kc) {
#pragma unroll
        for (int q = 0; q < 4; ++q) {
            float4 u = *(const float4*)(ap + kc * 64 + q * 8);
            float4 v = *(const float4*)(ap + kc * 64 + q * 8 + 4);
            *(f16x8*)&Al[sr * 72 + kh + q * 8] = pack8(u, v);
        }
#pragma unroll
        for (int q = 0; q < 4; ++q) {
            float4 u = *(const float4*)(bp + kc * 64 + q * 8);
            float4 v = *(const float4*)(bp + kc * 64 + q * 8 + 4);
            *(f16x8*)&Bl[sr * 72 + kh + q * 8] = pack8(u, v);
        }
        __syncthreads();

#pragma unroll
        for (int kk = 0; kk < 2; ++kk) {
            f16x8 bfr[4];
#pragma unroll
            for (int nb = 0; nb < 4; ++nb)
                bfr[nb] = *(const f16x8*)&Bl[(nw * 64 + nb * 16 + n) * 72 + kk * 32 + quad * 8];
#pragma unroll
            for (int mb = 0; mb < 4; ++mb) {
                f16x8 afr = *(const f16x8*)&Al[(mw * 64 + mb * 16 + n) * 72 + kk * 32 + quad * 8];
#pragma unroll
                for (int nb = 0; nb < 4; ++nb)
                    acc[mb][nb] = __builtin_amdgcn_mfma_f32_16x16x32_f16(
                        afr, bfr[nb], acc[mb][nb], 0, 0, 0);
            }
        }
        __syncthreads();
    }

    int   cc[4];
    float bv[4];
#pragma unroll
    for (int nb = 0; nb < 4; ++nb) {
        cc[nb] = n0 + nw * 64 + nb * 16 + n;
        bv[nb] = bih[cc[nb]] + bhh[cc[nb]];
    }
#pragma unroll
    for (int mb = 0; mb < 4; ++mb) {
        int rowg = m0 + mw * 64 + mb * 16 + quad * 4;
#pragma unroll
        for (int nb = 0; nb < 4; ++nb) {
#pragma unroll
            for (int i = 0; i < 4; ++i)
                out[(size_t)(rowg + i) * HH + cc[nb]] = acc[mb][nb][i] + bv[nb];
        }
    }
}

__global__ __launch_bounds__(512, 1) void phase2(
    const float* __restrict__ Whh, float* __restrict__ out) {
    __shared__ __align__(16) unsigned char himg[2][512];

    const int tid  = threadIdx.x;
    const int b    = blockIdx.x;
    const int wv   = tid >> 6;
    const int lane = tid & 63;
    const int n    = lane & 15;
    const int quad = lane >> 4;

    iv4 areg[4][8];
#pragma unroll
    for (int mb = 0; mb < 4; ++mb) {
        const float* wr = Whh + (size_t)(wv * 64 + mb * 16 + n) * HH + quad * 16;
#pragma unroll
        for (int j = 0; j < 8; ++j) {
            int kb = (j < 7) ? ((wv + 1 + j) & 7) : wv;
            const float4* p = (const float4*)(wr + kb * 64);
            iv4 v;
            v[0] = packw4(p[0]);
            v[1] = packw4(p[1]);
            v[2] = packw4(p[2]);
            v[3] = packw4(p[3]);
            areg[mb][j] = v;
        }
    }
    if (tid < 64) ((u64*)himg[0])[tid] = 0ull;
    __syncthreads();

    const int  ilo = n & 1;
    const int  ihi = (n >> 1) & 1;
    const bool sb0 = ((n >> 2) & 1) != 0;
    const bool sb1 = ((n >> 3) & 1) != 0;
    const int  row = wv * 64 + ((n >> 2) & 3) * 16 + quad * 4 + (n & 3);
    float* obase = out + (size_t)b * (SS * HH) + row;

    int koff[7];
#pragma unroll
    for (int j = 0; j < 7; ++j) koff[j] = ((wv + 1 + j) & 7) * 64 + quad * 16;
    const int oown = wv * 64 + quad * 16;

    const float inv2 = (2.0f * 1.4426950408889634f) / (SW * 127.0f);
    const float K2   = 2.0f * 1.4426950408889634f;

    iv4 acc0 = (iv4){0,0,0,0}, acc1 = (iv4){0,0,0,0};
    iv4 acc2 = (iv4){0,0,0,0}, acc3 = (iv4){0,0,0,0};

    float xp2_c = obase[0] * K2;
    float xp2_n = obase[HH] * K2;
    float hl = 0.f;
    unsigned char* h0p = himg[0];
    unsigned char* h1p = himg[1];

#define RNN_STEP(T, HBR, HNX)                                                  \
    {                                                                          \
        float xp_f = obase[(size_t)((T) + 2) * HH];                            \
        _Pragma("unroll")                                                      \
        for (int j = 0; j < 7; ++j) {                                          \
            iv4 bfr = *(const iv4*)((HBR) + koff[j]);                          \
            acc0 = __builtin_amdgcn_mfma_i32_16x16x64_i8(areg[0][j], bfr, acc0, 0, 0, 0); \
            acc1 = __builtin_amdgcn_mfma_i32_16x16x64_i8(areg[1][j], bfr, acc1, 0, 0, 0); \
            acc2 = __builtin_amdgcn_mfma_i32_16x16x64_i8(areg[2][j], bfr, acc2, 0, 0, 0); \
            acc3 = __builtin_amdgcn_mfma_i32_16x16x64_i8(areg[3][j], bfr, acc3, 0, 0, 0); \
        }                                                                      \
        iv4 sa = sb0 ? acc1 : acc0;                                            \
        iv4 sc = sb0 ? acc3 : acc2;                                            \
        iv4 s  = sb1 ? sc : sa;                                                \
        int zA = ilo ? s[1] : s[0];                                            \
        int zB = ilo ? s[3] : s[2];                                            \
        int z  = ihi ? zB : zA;                                                \
        float u  = fmaf((float)z, inv2, xp2_c);                                \
        float ex;                                                              \
        __asm__("v_exp_f32 %0, %1" : "=v"(ex) : "v"(u));                       \
        float rr = __builtin_amdgcn_rcpf(ex + 1.0f);                           \
        int   qv = (int)rintf(fmaf(rr, -254.0f, 127.0f));                      \
        *(char*)((HNX) + row) = (char)qv;                                      \
        iv4 bown = *(const iv4*)((HNX) + oown);                                \
        acc0 = __builtin_amdgcn_mfma_i32_16x16x64_i8(areg[0][7], bown, (iv4){0,0,0,0}, 0, 0, 0); \
        acc1 = __builtin_amdgcn_mfma_i32_16x16x64_i8(areg[1][7], bown, (iv4){0,0,0,0}, 0, 0, 0); \
        acc2 = __builtin_amdgcn_mfma_i32_16x16x64_i8(areg[2][7], bown, (iv4){0,0,0,0}, 0, 0, 0); \
        acc3 = __builtin_amdgcn_mfma_i32_16x16x64_i8(areg[3][7], bown, (iv4){0,0,0,0}, 0, 0, 0); \
        float h = fmaf(rr, -2.0f, 1.0f);                                       \
        obase[(size_t)(T) * HH] = h;                                           \
        hl = h;                                                                \
        __builtin_amdgcn_sched_barrier(0);                                     \
        __asm__ volatile("s_waitcnt lgkmcnt(0)\n\ts_barrier" ::: "memory");    \
        xp2_c = xp2_n; xp2_n = xp_f * K2;                                      \
    }

    for (int t = 0; t < SS; t += 2) {
        RNN_STEP(t,     h0p, h1p);
        RNN_STEP(t + 1, h1p, h0p);
    }
#undef RNN_STEP

    out[BSH + (size_t)b * HH + row] = hl;
}

extern "C" void kernel_launch(void* const* d_in, const int* in_sizes, int n_in,
                              void* d_out, int out_size, void* d_ws, size_t ws_size,
                              hipStream_t stream) {
    const int*   idx = (const int*)d_in[0];
    const float* emb = (const float*)d_in[1];
    const float* Wih = (const float*)d_in[2];
    const float* Whh = (const float*)d_in[3];
    const float* bih = (const float*)d_in[4];
    const float* bhh = (const float*)d_in[5];
    float* out = (float*)d_out;

    const size_t CNTBYTES = 260 * sizeof(unsigned int);  // 256 tiles + quant flag
    const size_t W8OFF    = 4096;
    const size_t NEED     = W8OFF + (size_t)HH * HH;     // + 256 KB i8 Whh

    if (d_ws && ws_size >= NEED) {
        unsigned int*  cnt  = (unsigned int*)d_ws;
        unsigned char* whh8 = (unsigned char*)d_ws + W8OFF;
        hipMemsetAsync(cnt, 0, CNTBYTES, stream);
        fused12<<<dim3(400), dim3(512), 0, stream>>>(
            idx, emb, Wih, bih, bhh, Whh, out, cnt, whh8);
    } else {
        phase1<<<dim3(1024), dim3(256), 0, stream>>>(idx, emb, Wih, bih, bhh, out);
        phase2<<<dim3(64), dim3(512), 0, stream>>>(Whh, out);
    }
}